// Round 1
// baseline (102.124 us; speedup 1.0000x reference)
//
#include <hip/hip_runtime.h>

// Signature_72327249265296: depth-4 path signature, path [64,512,10] fp32.
// out[b] = concat(A1[10], A2[100], A3[1000], A4[10000]).
//
// Horner-collapsed Chen step (per increment dx, all states start at 0):
//   p1 = A1/6 + dx_i/24 ; q1 = A1/2 + dx_i/6 ; r1 = A1 + dx_i/2
//   p2 = A2/2 + p1*dx_j ; q2 = A2 + q1*dx_j  ; A2 += r1*dx_j
//   p3 = A3 + p2*dx_k   ;                      A3 += q2*dx_k
//   A1 += dx_i
//   A4[l] += p3*dx_l   (l = 0..9)
// One lane owns one (b,i,j,k) chain: state = 13 registers, no cross-lane
// communication inside the 511-step loop (dx rows are read-only LDS).

#define CH      10
#define NSTEPS  511
#define ROW     12                 // padded dx row in floats (48 B, 16B-aligned)
#define SIGSZ   11110              // 10 + 100 + 1000 + 10000

__global__ __launch_bounds__(256, 1)
void sig_kernel(const float* __restrict__ path, float* __restrict__ out) {
    __shared__ __align__(16) float dxL[NSTEPS * ROW];

    const int tid  = threadIdx.x;
    const int b    = blockIdx.x >> 2;   // batch index 0..63
    const int part = blockIdx.x & 3;    // which 256-chain slice of the 1000

    // ---- stage all increments for this batch into LDS (coalesced) ----
    const float* p = path + b * (512 * CH);
    for (int e = tid; e < NSTEPS * CH; e += 256) {
        int s = e / CH;
        int c = e - s * CH;
        dxL[s * ROW + c] = p[e + CH] - p[e];
    }
    __syncthreads();

    const int id = part * 256 + tid;    // chain id = i*100 + j*10 + k
    if (id < 1000) {
        const int ci = id / 100;
        const int cj = (id / 10) % 10;
        const int ck = id % 10;

        float a1 = 0.f, a2 = 0.f, a3 = 0.f;
        float a4[10];
        #pragma unroll
        for (int l = 0; l < 10; ++l) a4[l] = 0.f;

        #pragma unroll 4
        for (int s = 0; s < NSTEPS; ++s) {
            const float* row = dxL + s * ROW;
            // broadcast reads (all lanes same address -> conflict-free)
            const float4 d0 = *(const float4*)(row);
            const float4 d1 = *(const float4*)(row + 4);
            const float2 d2 = *(const float2*)(row + 8);
            // lane-indexed reads (<=10 distinct consecutive addrs -> distinct banks)
            const float dxi = row[ci];
            const float dxj = row[cj];
            const float dxk = row[ck];

            const float p1 = a1 * (1.f / 6.f)  + dxi * (1.f / 24.f);
            const float q1 = a1 * 0.5f         + dxi * (1.f / 6.f);
            const float r1 = a1                + dxi * 0.5f;
            const float p2 = a2 * 0.5f + p1 * dxj;
            const float q2 = a2        + q1 * dxj;
            a2 += r1 * dxj;
            const float p3 = a3 + p2 * dxk;
            a3 += q2 * dxk;
            a1 += dxi;

            a4[0] += p3 * d0.x; a4[1] += p3 * d0.y;
            a4[2] += p3 * d0.z; a4[3] += p3 * d0.w;
            a4[4] += p3 * d1.x; a4[5] += p3 * d1.y;
            a4[6] += p3 * d1.z; a4[7] += p3 * d1.w;
            a4[8] += p3 * d2.x; a4[9] += p3 * d2.y;
        }

        // ---- epilogue: write this chain's share of the signature ----
        float* ob = out + b * SIGSZ;
        float* o4 = ob + 1110 + id * 10;
        #pragma unroll
        for (int l = 0; l < 10; ++l) o4[l] = a4[l];
        ob[110 + id] = a3;
        if (ck == 0)            ob[10 + ci * 10 + cj] = a2;
        if (ck == 0 && cj == 0) ob[ci] = a1;
    }
}

extern "C" void kernel_launch(void* const* d_in, const int* in_sizes, int n_in,
                              void* d_out, int out_size, void* d_ws, size_t ws_size,
                              hipStream_t stream) {
    const float* path = (const float*)d_in[0];   // [64, 512, 10] fp32
    // d_in[1] = depth (=4), structure hard-coded above
    float* out = (float*)d_out;                  // [64, 11110] fp32
    sig_kernel<<<dim3(256), dim3(256), 0, stream>>>(path, out);
}